// Round 7
// baseline (223.000 us; speedup 1.0000x reference)
//
#include <hip/hip_runtime.h>
#include <math.h>

#define NJ 24
#define NV 6890
#define NB 10
#define KREAL 217
#define KP 224      // K padded to 7 chunks of 32
#define NVT 432     // ceil(NV/16) vertex tiles of 16

typedef __attribute__((ext_vector_type(8))) short bf16x8;
typedef __attribute__((ext_vector_type(8))) unsigned short u16x8;
typedef __attribute__((ext_vector_type(4))) float f32x4;

__device__ __forceinline__ unsigned short f2bf(float x) {
    unsigned int u = __float_as_uint(x);
    u += 0x7fffu + ((u >> 16) & 1u);
    return (unsigned short)(u >> 16);
}
__device__ __forceinline__ float bf2f(unsigned short h) {
    return __uint_as_float(((unsigned int)h) << 16);
}

__device__ __constant__ int c_path[NJ][9] = {
  {0,0,0,0,0,0,0,0,0},
  {0,1,0,0,0,0,0,0,0},
  {0,2,0,0,0,0,0,0,0},
  {0,3,0,0,0,0,0,0,0},
  {0,1,4,0,0,0,0,0,0},
  {0,2,5,0,0,0,0,0,0},
  {0,3,6,0,0,0,0,0,0},
  {0,1,4,7,0,0,0,0,0},
  {0,2,5,8,0,0,0,0,0},
  {0,3,6,9,0,0,0,0,0},
  {0,1,4,7,10,0,0,0,0},
  {0,2,5,8,11,0,0,0,0},
  {0,3,6,9,12,0,0,0,0},
  {0,3,6,9,13,0,0,0,0},
  {0,3,6,9,14,0,0,0,0},
  {0,3,6,9,12,15,0,0,0},
  {0,3,6,9,13,16,0,0,0},
  {0,3,6,9,14,17,0,0,0},
  {0,3,6,9,13,16,18,0,0},
  {0,3,6,9,14,17,19,0,0},
  {0,3,6,9,13,16,18,20,0},
  {0,3,6,9,14,17,19,21,0},
  {0,3,6,9,13,16,18,20,22},
  {0,3,6,9,14,17,19,21,23}};
__device__ __constant__ int c_plen[NJ] = {1,2,2,2,3,3,3,4,4,4,5,5,5,5,5,6,6,6,7,7,8,8,9,9};

// ---------------------------------------------------------------------------
// Kernel 1: coalesced pack of dirs into certified MFMA A-fragment order.
// (verbatim R6-certified)
// ---------------------------------------------------------------------------
__global__ __launch_bounds__(256)
void pack_kernel(const float* __restrict__ shapedirs, const float* __restrict__ posedirs,
                 unsigned short* __restrict__ dirsF)
{
    __shared__ unsigned short tile[16][3][240];
    const int t = threadIdx.x;
    const int vtg = blockIdx.x;

    for (int idx = t; idx < 16 * 3 * KP; idx += 256) {
        const int v_l = idx / (3 * KP);
        const int rem = idx - v_l * (3 * KP);
        const int c = rem / KP;
        const int k = rem - c * KP;
        const int v = vtg * 16 + v_l;
        float val = 0.f;
        if (v < NV && k < KREAL)
            val = (k < NB) ? shapedirs[(size_t)v * 30 + c * NB + k]
                           : posedirs[(size_t)v * 621 + c * 207 + (k - NB)];
        tile[v_l][c][k] = f2bf(val);
    }
    __syncthreads();

    const int lane = t & 63;
    const int w = t >> 6;
    const int kg = lane >> 4;
    const int vsub = lane & 15;
    for (int j2 = w; j2 < 21; j2 += 4) {
        const int kt = j2 / 3;
        const int c = j2 - kt * 3;
        const u16x8 o = *(const u16x8*)&tile[vsub][c][kt * 32 + kg * 8];
        *(u16x8*)&dirsF[(((size_t)(kt * 3 + c) * NVT + vtg) * 64 + lane) * 8] = o;
    }
}

// ---------------------------------------------------------------------------
// Kernel 2: per-batch prep. Certified math; emits coeffF (certified) plus
// AF (bf16-hi B-frags of [R|T], e=0..11) and AFL (lo frags for T cols only).
// ---------------------------------------------------------------------------
__global__ __launch_bounds__(64)
void prep_kernel(const float* __restrict__ pose, const float* __restrict__ betas,
                 const float* __restrict__ trans, const float* __restrict__ J_template,
                 const float* __restrict__ J_shapedirs,
                 float* __restrict__ joints_out, float* __restrict__ glob_out,
                 unsigned short* __restrict__ AF, unsigned short* __restrict__ AFL,
                 unsigned short* __restrict__ coeffF, int B)
{
    const int b = blockIdx.x;
    const int t = threadIdx.x;
    __shared__ float s_beta[NB];
    __shared__ float s_rel[NJ][9];
    __shared__ float s_glob[NJ][9];
    __shared__ float s_j[NJ][3];
    __shared__ float s_A[NJ][12];

    if (t < NB) s_beta[t] = betas[b * NB + t];
    __syncthreads();

    if (t < NJ) {
        float rx = pose[b * 72 + t * 3 + 0];
        float ry = pose[b * 72 + t * 3 + 1];
        float rz = pose[b * 72 + t * 3 + 2];
        float th = sqrtf(rx * rx + ry * ry + rz * rz);
        float safe = (th < 1e-8f) ? 1.0f : th;
        float ax = rx / safe, ay = ry / safe, az = rz / safe;
        float s = sinf(th), c = cosf(th), omc = 1.0f - c;
        float aa = ax * ax + ay * ay + az * az;
        float K[9] = {0.f, -az, ay, az, 0.f, -ax, -ay, ax, 0.f};
        float A2[9] = {ax*ax - aa, ax*ay,      ax*az,
                       ay*ax,      ay*ay - aa, ay*az,
                       az*ax,      az*ay,      az*az - aa};
        #pragma unroll
        for (int r = 0; r < 3; ++r)
            #pragma unroll
            for (int cc = 0; cc < 3; ++cc)
                s_rel[t][r * 3 + cc] = ((r == cc) ? 1.0f : 0.0f)
                                     + s * K[r * 3 + cc] + omc * A2[r * 3 + cc];
        #pragma unroll
        for (int cc = 0; cc < 3; ++cc) {
            float acc = J_template[t * 3 + cc];
            #pragma unroll
            for (int q = 0; q < NB; ++q)
                acc = fmaf(J_shapedirs[(t * 3 + cc) * NB + q], s_beta[q], acc);
            s_j[t][cc] = acc;
        }
    }
    __syncthreads();

    if (t < NJ) {
        const int L = c_plen[t];
        float G[9];
        #pragma unroll
        for (int e = 0; e < 9; ++e) G[e] = s_rel[0][e];
        for (int sIdx = 1; sIdx < L; ++sIdx) {
            const int p = c_path[t][sIdx];
            float Tn[9];
            #pragma unroll
            for (int r = 0; r < 3; ++r)
                #pragma unroll
                for (int cc = 0; cc < 3; ++cc)
                    Tn[r * 3 + cc] = G[r * 3 + 0] * s_rel[p][0 * 3 + cc]
                                   + G[r * 3 + 1] * s_rel[p][1 * 3 + cc]
                                   + G[r * 3 + 2] * s_rel[p][2 * 3 + cc];
            #pragma unroll
            for (int e = 0; e < 9; ++e) G[e] = Tn[e];
        }
        #pragma unroll
        for (int e = 0; e < 9; ++e) s_glob[t][e] = G[e];
        #pragma unroll
        for (int e = 0; e < 9; ++e) glob_out[(size_t)b * 216 + t * 9 + e] = G[e];
    }
    __syncthreads();

    if (t < NJ) {
        const int L = c_plen[t];
        float px = s_j[0][0], py = s_j[0][1], pz = s_j[0][2];
        for (int sIdx = 1; sIdx < L; ++sIdx) {
            const int pk = c_path[t][sIdx];
            const int pp = c_path[t][sIdx - 1];
            float bx = s_j[pk][0] - s_j[pp][0];
            float by = s_j[pk][1] - s_j[pp][1];
            float bz = s_j[pk][2] - s_j[pp][2];
            px += s_glob[pp][0] * bx + s_glob[pp][1] * by + s_glob[pp][2] * bz;
            py += s_glob[pp][3] * bx + s_glob[pp][4] * by + s_glob[pp][5] * bz;
            pz += s_glob[pp][6] * bx + s_glob[pp][7] * by + s_glob[pp][8] * bz;
        }
        const float tx = trans[b * 3 + 0], ty = trans[b * 3 + 1], tz = trans[b * 3 + 2];
        joints_out[(size_t)b * 72 + t * 3 + 0] = px + tx;
        joints_out[(size_t)b * 72 + t * 3 + 1] = py + ty;
        joints_out[(size_t)b * 72 + t * 3 + 2] = pz + tz;
        const float jx = s_j[t][0], jy = s_j[t][1], jz = s_j[t][2];
        float T0 = px - (s_glob[t][0] * jx + s_glob[t][1] * jy + s_glob[t][2] * jz) + tx;
        float T1 = py - (s_glob[t][3] * jx + s_glob[t][4] * jy + s_glob[t][5] * jz) + ty;
        float T2 = pz - (s_glob[t][6] * jx + s_glob[t][7] * jy + s_glob[t][8] * jz) + tz;
        s_A[t][0]  = s_glob[t][0]; s_A[t][1]  = s_glob[t][1]; s_A[t][2]  = s_glob[t][2]; s_A[t][3]  = T0;
        s_A[t][4]  = s_glob[t][3]; s_A[t][5]  = s_glob[t][4]; s_A[t][6]  = s_glob[t][5]; s_A[t][7]  = T1;
        s_A[t][8]  = s_glob[t][6]; s_A[t][9]  = s_glob[t][7]; s_A[t][10] = s_glob[t][8]; s_A[t][11] = T2;
    }
    __syncthreads();

    const int btg = b >> 4, bl = b & 15, bt_ = (b >> 4) & 3;
    // coeffF B-frags (certified)
    for (int k = t; k < KP; k += 64) {
        float val;
        if (k < NB) val = s_beta[k];
        else if (k < KREAL) { const int p2 = k - NB; val = s_rel[1 + p2 / 9][p2 % 9]; }
        else val = 0.f;
        const int kt = k >> 5, kg = (k >> 3) & 3, i = k & 7;
        coeffF[(((size_t)kt * (B >> 4) + btg) * 64 + kg * 16 + bl) * 8 + i] = f2bf(val);
    }
    // AF hi B-frags: A[b][j][e], j padded 24->32 with zeros
    for (int idx = t; idx < 12 * 32; idx += 64) {
        const int e = idx >> 5, jj = idx & 31, kg = jj >> 3, i = jj & 7;
        const float val = (jj < NJ) ? s_A[jj][e] : 0.f;
        AF[((((size_t)(b >> 6) * 12 + e) * 4 + bt_) * 64 + kg * 16 + bl) * 8 + i] = f2bf(val);
    }
    // AFL lo B-frags for T columns only: et=0..2 <-> e = et*4+3
    for (int idx = t; idx < 3 * 32; idx += 64) {
        const int et = idx >> 5, jj = idx & 31, kg = jj >> 3, i = jj & 7;
        const float val = (jj < NJ) ? s_A[jj][et * 4 + 3] : 0.f;
        const unsigned short hi = f2bf(val);
        AFL[((((size_t)(b >> 6) * 3 + et) * 4 + bt_) * 64 + kg * 16 + bl) * 8 + i]
            = f2bf(val - bf2f(hi));
    }
}

// ---------------------------------------------------------------------------
// Kernel 3: certified MFMA GEMM1 + MFMA LBS blend (w built in-register from
// raw fp32 weights, hi/lo) + R6-CERTIFIED ep-transpose & scatter store.
// Grid (B/64, 108) x 256 (4 waves), wave = vtile.
// ---------------------------------------------------------------------------
__global__ __launch_bounds__(256)
void vert_kernel(const float4* __restrict__ dirsF, const float4* __restrict__ coeffF,
                 const float4* __restrict__ AF, const float4* __restrict__ AFL,
                 const float* __restrict__ v_template, const float* __restrict__ weights,
                 float* __restrict__ vert_out, int B)
{
    __shared__ float smem[6336];    // 25,344 B: dirs chunk (12KB) / ep[3][32][66]
    const int tid  = threadIdx.x;
    const int lane = tid & 63;
    const int w    = __builtin_amdgcn_readfirstlane(tid >> 6);   // 0..3
    const int vt   = w;
    const int vb4  = blockIdx.y * 4;
    const int bblk = blockIdx.x;
    const int nbt  = B >> 4;

    f32x4 acc[3][4];
    #pragma unroll
    for (int c = 0; c < 3; ++c)
        #pragma unroll
        for (int bt = 0; bt < 4; ++bt) {
            acc[c][bt][0] = 0.f; acc[c][bt][1] = 0.f; acc[c][bt][2] = 0.f; acc[c][bt][3] = 0.f;
        }

    for (int kt = 0; kt < 7; ++kt) {
        __syncthreads();
        #pragma unroll
        for (int s = 0; s < 3; ++s) {
            const int row = s * 256 + tid;
            const int ch = row >> 6, l2 = row & 63;
            *(float4*)&smem[row * 4] =
                dirsF[((size_t)(kt * 3 + (ch >> 2)) * NVT + vb4 + (ch & 3)) * 64 + l2];
        }
        __syncthreads();
        bf16x8 bq[4];
        #pragma unroll
        for (int bt = 0; bt < 4; ++bt)
            bq[bt] = *(const bf16x8*)&coeffF[((size_t)kt * nbt + bblk * 4 + bt) * 64 + lane];
        #pragma unroll
        for (int c = 0; c < 3; ++c) {
            const bf16x8 a = *(const bf16x8*)&smem[((c * 4 + vt) * 64 + lane) * 4];
            #pragma unroll
            for (int bt = 0; bt < 4; ++bt)
                acc[c][bt] = __builtin_amdgcn_mfma_f32_16x16x32_bf16(a, bq[bt], acc[c][bt], 0, 0, 0);
        }
    }

    // add v_template (certified)
    const int vrow0 = (vb4 + vt) * 16 + ((lane >> 4) << 2);
    #pragma unroll
    for (int c = 0; c < 3; ++c) {
        float tv[4];
        #pragma unroll
        for (int r = 0; r < 4; ++r) {
            const int v = vrow0 + r;
            tv[r] = (v < NV) ? v_template[(size_t)v * 3 + c] : 0.f;
        }
        #pragma unroll
        for (int bt = 0; bt < 4; ++bt) {
            acc[c][bt][0] += tv[0]; acc[c][bt][1] += tv[1];
            acc[c][bt][2] += tv[2]; acc[c][bt][3] += tv[3];
        }
    }

    // build weight A-frags IN-REGISTER from raw fp32 weights (hi/lo split).
    // A-map (certified via dirsF): row v = (vb4+vt)*16 + (lane&15),
    // j = (lane>>4)*8 + i ; octet kg==3 (j=24..31) is zero padding.
    bf16x8 wh, wl;
    {
        const int vA = (vb4 + vt) * 16 + (lane & 15);
        const int kg = lane >> 4;
        if (kg < 3 && vA < NV) {
            const float* wp = weights + (size_t)vA * NJ + kg * 8;
            #pragma unroll
            for (int i = 0; i < 8; ++i) {
                const float val = wp[i];
                const unsigned short hi = f2bf(val);
                wh[i] = (short)hi;
                wl[i] = (short)f2bf(val - bf2f(hi));
            }
        } else {
            #pragma unroll
            for (int i = 0; i < 8; ++i) { wh[i] = 0; wl[i] = 0; }
        }
    }

    __syncthreads();   // all waves done reading dirs LDS

    f32x4 zero; zero[0] = 0.f; zero[1] = 0.f; zero[2] = 0.f; zero[3] = 0.f;
    const int vglob = vb4 * 16 + lane;

    for (int p = 0; p < 2; ++p) {
        if (p) __syncthreads();   // pass-0 readers done before ep overwrite
        #pragma unroll
        for (int half = 0; half < 2; ++half) {
            const int bt = 2 * p + half;
            #pragma unroll
            for (int C = 0; C < 3; ++C) {
                // T column e = C*4+3: out = wl*Thi + wh*Tlo + wh*Thi
                const size_t baseT  = (((size_t)bblk * 12 + (C * 4 + 3)) * 4 + bt) * 64 + lane;
                const size_t baseTL = (((size_t)bblk * 3 + C) * 4 + bt) * 64 + lane;
                const bf16x8 ATh = *(const bf16x8*)&AF[baseT];
                const bf16x8 ATl = *(const bf16x8*)&AFL[baseTL];
                f32x4 out = __builtin_amdgcn_mfma_f32_16x16x32_bf16(wl, ATh, zero, 0, 0, 0);
                out = __builtin_amdgcn_mfma_f32_16x16x32_bf16(wh, ATl, out, 0, 0, 0);
                out = __builtin_amdgcn_mfma_f32_16x16x32_bf16(wh, ATh, out, 0, 0, 0);
                #pragma unroll
                for (int q = 0; q < 3; ++q) {
                    const size_t baseR = (((size_t)bblk * 12 + (C * 4 + q)) * 4 + bt) * 64 + lane;
                    const bf16x8 ARh = *(const bf16x8*)&AF[baseR];
                    f32x4 rr = __builtin_amdgcn_mfma_f32_16x16x32_bf16(wl, ARh, zero, 0, 0, 0);
                    rr = __builtin_amdgcn_mfma_f32_16x16x32_bf16(wh, ARh, rr, 0, 0, 0);
                    out[0] = fmaf(rr[0], acc[q][bt][0], out[0]);
                    out[1] = fmaf(rr[1], acc[q][bt][1], out[1]);
                    out[2] = fmaf(rr[2], acc[q][bt][2], out[2]);
                    out[3] = fmaf(rr[3], acc[q][bt][3], out[3]);
                }
                // ep write — R6-certified mapping
                const int b32 = half * 16 + (lane & 15);
                const int vl  = vt * 16 + ((lane >> 4) << 2);
                smem[(C * 32 + b32) * 66 + vl + 0] = out[0];
                smem[(C * 32 + b32) * 66 + vl + 1] = out[1];
                smem[(C * 32 + b32) * 66 + vl + 2] = out[2];
                smem[(C * 32 + b32) * 66 + vl + 3] = out[3];
            }
        }
        __syncthreads();

        // R6-certified scatter store
        if (vglob < NV) {
            #pragma unroll
            for (int i = 0; i < 8; ++i) {
                const int b32 = w * 8 + i;
                const int b = bblk * 64 + p * 32 + b32;
                const float o0 = smem[(0 * 32 + b32) * 66 + lane];
                const float o1 = smem[(1 * 32 + b32) * 66 + lane];
                const float o2 = smem[(2 * 32 + b32) * 66 + lane];
                const size_t off = (size_t)b * (NV * 3) + (size_t)vglob * 3;
                vert_out[off + 0] = o0;
                vert_out[off + 1] = o1;
                vert_out[off + 2] = o2;
            }
        }
    }
}

// ---------------------------------------------------------------------------
extern "C" void kernel_launch(void* const* d_in, const int* in_sizes, int n_in,
                              void* d_out, int out_size, void* d_ws, size_t ws_size,
                              hipStream_t stream) {
    const float* pose        = (const float*)d_in[0];
    const float* betas       = (const float*)d_in[1];
    const float* trans       = (const float*)d_in[2];
    const float* v_template  = (const float*)d_in[3];
    const float* shapedirs   = (const float*)d_in[4];
    const float* posedirs    = (const float*)d_in[5];
    const float* J_template  = (const float*)d_in[6];
    const float* J_shapedirs = (const float*)d_in[7];
    const float* weights     = (const float*)d_in[8];
    const int B = in_sizes[0] / 72;   // 1024

    float* out = (float*)d_out;
    float* joints_out = out;                                        // B*72
    float* vert_out   = out + (size_t)B * 72;                       // B*NV*3
    float* glob_out   = out + (size_t)B * 72 + (size_t)B * NV * 3;  // B*216

    char* ws = (char*)d_ws;
    const size_t coeff_bytes = (size_t)7 * (B >> 4) * 64 * 16;       // 458,752
    const size_t af_bytes    = (size_t)(B >> 6) * 12 * 4 * 64 * 16;  // 786,432
    const size_t afl_bytes   = (size_t)(B >> 6) * 3 * 4 * 64 * 16;   // 196,608
    unsigned short* coeffF = (unsigned short*)ws;
    unsigned short* AF     = (unsigned short*)(ws + coeff_bytes);
    unsigned short* AFL    = (unsigned short*)(ws + coeff_bytes + af_bytes);
    unsigned short* dirsF  = (unsigned short*)(ws + coeff_bytes + af_bytes + afl_bytes);

    pack_kernel<<<dim3(NVT), 256, 0, stream>>>(shapedirs, posedirs, dirsF);
    prep_kernel<<<dim3(B), 64, 0, stream>>>(pose, betas, trans, J_template, J_shapedirs,
                                            joints_out, glob_out, AF, AFL, coeffF, B);
    vert_kernel<<<dim3(B / 64, 108), 256, 0, stream>>>((const float4*)dirsF, (const float4*)coeffF,
                                                       (const float4*)AF, (const float4*)AFL,
                                                       v_template, weights, vert_out, B);
}

// Round 8
// 205.554 us; speedup vs baseline: 1.0849x; 1.0849x over previous
//
#include <hip/hip_runtime.h>
#include <math.h>

#define NJ 24
#define NV 6890
#define NB 10
#define KREAL 217
#define KP 224      // K padded to 7 chunks of 32
#define NVT 432     // ceil(NV/16) vertex tiles of 16

typedef __attribute__((ext_vector_type(8))) short bf16x8;
typedef __attribute__((ext_vector_type(8))) unsigned short u16x8;
typedef __attribute__((ext_vector_type(4))) float f32x4;

__device__ __forceinline__ unsigned short f2bf(float x) {
    unsigned int u = __float_as_uint(x);
    u += 0x7fffu + ((u >> 16) & 1u);
    return (unsigned short)(u >> 16);
}
__device__ __forceinline__ float bf2f(unsigned short h) {
    return __uint_as_float(((unsigned int)h) << 16);
}

__device__ __constant__ int c_path[NJ][9] = {
  {0,0,0,0,0,0,0,0,0},
  {0,1,0,0,0,0,0,0,0},
  {0,2,0,0,0,0,0,0,0},
  {0,3,0,0,0,0,0,0,0},
  {0,1,4,0,0,0,0,0,0},
  {0,2,5,0,0,0,0,0,0},
  {0,3,6,0,0,0,0,0,0},
  {0,1,4,7,0,0,0,0,0},
  {0,2,5,8,0,0,0,0,0},
  {0,3,6,9,0,0,0,0,0},
  {0,1,4,7,10,0,0,0,0},
  {0,2,5,8,11,0,0,0,0},
  {0,3,6,9,12,0,0,0,0},
  {0,3,6,9,13,0,0,0,0},
  {0,3,6,9,14,0,0,0,0},
  {0,3,6,9,12,15,0,0,0},
  {0,3,6,9,13,16,0,0,0},
  {0,3,6,9,14,17,0,0,0},
  {0,3,6,9,13,16,18,0,0},
  {0,3,6,9,14,17,19,0,0},
  {0,3,6,9,13,16,18,20,0},
  {0,3,6,9,14,17,19,21,0},
  {0,3,6,9,13,16,18,20,22},
  {0,3,6,9,14,17,19,21,23}};
__device__ __constant__ int c_plen[NJ] = {1,2,2,2,3,3,3,4,4,4,5,5,5,5,5,6,6,6,7,7,8,8,9,9};

// ---------------------------------------------------------------------------
// Kernel 1: coalesced pack of dirs into certified MFMA A-fragment order.
// (verbatim R6/R7-certified)
// ---------------------------------------------------------------------------
__global__ __launch_bounds__(256)
void pack_kernel(const float* __restrict__ shapedirs, const float* __restrict__ posedirs,
                 unsigned short* __restrict__ dirsF)
{
    __shared__ unsigned short tile[16][3][240];
    const int t = threadIdx.x;
    const int vtg = blockIdx.x;

    for (int idx = t; idx < 16 * 3 * KP; idx += 256) {
        const int v_l = idx / (3 * KP);
        const int rem = idx - v_l * (3 * KP);
        const int c = rem / KP;
        const int k = rem - c * KP;
        const int v = vtg * 16 + v_l;
        float val = 0.f;
        if (v < NV && k < KREAL)
            val = (k < NB) ? shapedirs[(size_t)v * 30 + c * NB + k]
                           : posedirs[(size_t)v * 621 + c * 207 + (k - NB)];
        tile[v_l][c][k] = f2bf(val);
    }
    __syncthreads();

    const int lane = t & 63;
    const int w = t >> 6;
    const int kg = lane >> 4;
    const int vsub = lane & 15;
    for (int j2 = w; j2 < 21; j2 += 4) {
        const int kt = j2 / 3;
        const int c = j2 - kt * 3;
        const u16x8 o = *(const u16x8*)&tile[vsub][c][kt * 32 + kg * 8];
        *(u16x8*)&dirsF[(((size_t)(kt * 3 + c) * NVT + vtg) * 64 + lane) * 8] = o;
    }
}

// ---------------------------------------------------------------------------
// Kernel 2: per-batch prep (verbatim R7-certified).
// ---------------------------------------------------------------------------
__global__ __launch_bounds__(64)
void prep_kernel(const float* __restrict__ pose, const float* __restrict__ betas,
                 const float* __restrict__ trans, const float* __restrict__ J_template,
                 const float* __restrict__ J_shapedirs,
                 float* __restrict__ joints_out, float* __restrict__ glob_out,
                 unsigned short* __restrict__ AF, unsigned short* __restrict__ AFL,
                 unsigned short* __restrict__ coeffF, int B)
{
    const int b = blockIdx.x;
    const int t = threadIdx.x;
    __shared__ float s_beta[NB];
    __shared__ float s_rel[NJ][9];
    __shared__ float s_glob[NJ][9];
    __shared__ float s_j[NJ][3];
    __shared__ float s_A[NJ][12];

    if (t < NB) s_beta[t] = betas[b * NB + t];
    __syncthreads();

    if (t < NJ) {
        float rx = pose[b * 72 + t * 3 + 0];
        float ry = pose[b * 72 + t * 3 + 1];
        float rz = pose[b * 72 + t * 3 + 2];
        float th = sqrtf(rx * rx + ry * ry + rz * rz);
        float safe = (th < 1e-8f) ? 1.0f : th;
        float ax = rx / safe, ay = ry / safe, az = rz / safe;
        float s = sinf(th), c = cosf(th), omc = 1.0f - c;
        float aa = ax * ax + ay * ay + az * az;
        float K[9] = {0.f, -az, ay, az, 0.f, -ax, -ay, ax, 0.f};
        float A2[9] = {ax*ax - aa, ax*ay,      ax*az,
                       ay*ax,      ay*ay - aa, ay*az,
                       az*ax,      az*ay,      az*az - aa};
        #pragma unroll
        for (int r = 0; r < 3; ++r)
            #pragma unroll
            for (int cc = 0; cc < 3; ++cc)
                s_rel[t][r * 3 + cc] = ((r == cc) ? 1.0f : 0.0f)
                                     + s * K[r * 3 + cc] + omc * A2[r * 3 + cc];
        #pragma unroll
        for (int cc = 0; cc < 3; ++cc) {
            float acc = J_template[t * 3 + cc];
            #pragma unroll
            for (int q = 0; q < NB; ++q)
                acc = fmaf(J_shapedirs[(t * 3 + cc) * NB + q], s_beta[q], acc);
            s_j[t][cc] = acc;
        }
    }
    __syncthreads();

    if (t < NJ) {
        const int L = c_plen[t];
        float G[9];
        #pragma unroll
        for (int e = 0; e < 9; ++e) G[e] = s_rel[0][e];
        for (int sIdx = 1; sIdx < L; ++sIdx) {
            const int p = c_path[t][sIdx];
            float Tn[9];
            #pragma unroll
            for (int r = 0; r < 3; ++r)
                #pragma unroll
                for (int cc = 0; cc < 3; ++cc)
                    Tn[r * 3 + cc] = G[r * 3 + 0] * s_rel[p][0 * 3 + cc]
                                   + G[r * 3 + 1] * s_rel[p][1 * 3 + cc]
                                   + G[r * 3 + 2] * s_rel[p][2 * 3 + cc];
            #pragma unroll
            for (int e = 0; e < 9; ++e) G[e] = Tn[e];
        }
        #pragma unroll
        for (int e = 0; e < 9; ++e) s_glob[t][e] = G[e];
        #pragma unroll
        for (int e = 0; e < 9; ++e) glob_out[(size_t)b * 216 + t * 9 + e] = G[e];
    }
    __syncthreads();

    if (t < NJ) {
        const int L = c_plen[t];
        float px = s_j[0][0], py = s_j[0][1], pz = s_j[0][2];
        for (int sIdx = 1; sIdx < L; ++sIdx) {
            const int pk = c_path[t][sIdx];
            const int pp = c_path[t][sIdx - 1];
            float bx = s_j[pk][0] - s_j[pp][0];
            float by = s_j[pk][1] - s_j[pp][1];
            float bz = s_j[pk][2] - s_j[pp][2];
            px += s_glob[pp][0] * bx + s_glob[pp][1] * by + s_glob[pp][2] * bz;
            py += s_glob[pp][3] * bx + s_glob[pp][4] * by + s_glob[pp][5] * bz;
            pz += s_glob[pp][6] * bx + s_glob[pp][7] * by + s_glob[pp][8] * bz;
        }
        const float tx = trans[b * 3 + 0], ty = trans[b * 3 + 1], tz = trans[b * 3 + 2];
        joints_out[(size_t)b * 72 + t * 3 + 0] = px + tx;
        joints_out[(size_t)b * 72 + t * 3 + 1] = py + ty;
        joints_out[(size_t)b * 72 + t * 3 + 2] = pz + tz;
        const float jx = s_j[t][0], jy = s_j[t][1], jz = s_j[t][2];
        float T0 = px - (s_glob[t][0] * jx + s_glob[t][1] * jy + s_glob[t][2] * jz) + tx;
        float T1 = py - (s_glob[t][3] * jx + s_glob[t][4] * jy + s_glob[t][5] * jz) + ty;
        float T2 = pz - (s_glob[t][6] * jx + s_glob[t][7] * jy + s_glob[t][8] * jz) + tz;
        s_A[t][0]  = s_glob[t][0]; s_A[t][1]  = s_glob[t][1]; s_A[t][2]  = s_glob[t][2]; s_A[t][3]  = T0;
        s_A[t][4]  = s_glob[t][3]; s_A[t][5]  = s_glob[t][4]; s_A[t][6]  = s_glob[t][5]; s_A[t][7]  = T1;
        s_A[t][8]  = s_glob[t][6]; s_A[t][9]  = s_glob[t][7]; s_A[t][10] = s_glob[t][8]; s_A[t][11] = T2;
    }
    __syncthreads();

    const int btg = b >> 4, bl = b & 15, bt_ = (b >> 4) & 3;
    for (int k = t; k < KP; k += 64) {
        float val;
        if (k < NB) val = s_beta[k];
        else if (k < KREAL) { const int p2 = k - NB; val = s_rel[1 + p2 / 9][p2 % 9]; }
        else val = 0.f;
        const int kt = k >> 5, kg = (k >> 3) & 3, i = k & 7;
        coeffF[(((size_t)kt * (B >> 4) + btg) * 64 + kg * 16 + bl) * 8 + i] = f2bf(val);
    }
    for (int idx = t; idx < 12 * 32; idx += 64) {
        const int e = idx >> 5, jj = idx & 31, kg = jj >> 3, i = jj & 7;
        const float val = (jj < NJ) ? s_A[jj][e] : 0.f;
        AF[((((size_t)(b >> 6) * 12 + e) * 4 + bt_) * 64 + kg * 16 + bl) * 8 + i] = f2bf(val);
    }
    for (int idx = t; idx < 3 * 32; idx += 64) {
        const int et = idx >> 5, jj = idx & 31, kg = jj >> 3, i = jj & 7;
        const float val = (jj < NJ) ? s_A[jj][et * 4 + 3] : 0.f;
        const unsigned short hi = f2bf(val);
        AFL[((((size_t)(b >> 6) * 3 + et) * 4 + bt_) * 64 + kg * 16 + bl) * 8 + i]
            = f2bf(val - bf2f(hi));
    }
}

// ---------------------------------------------------------------------------
// Kernel 3: MFMA GEMM1 (async double-buffered staging) + certified MFMA blend
// + full-line contiguous float2 stores (no RFO).
// Grid (B/64, 108) x 256 (4 waves), wave = vtile.
// ---------------------------------------------------------------------------
__global__ __launch_bounds__(256)
void vert_kernel(const float4* __restrict__ dirsF, const float4* __restrict__ coeffF,
                 const float4* __restrict__ AF, const float4* __restrict__ AFL,
                 const float* __restrict__ v_template, const float* __restrict__ weights,
                 float* __restrict__ vert_out, int B)
{
    __shared__ float smem[6336];    // 25,344 B: dirs chunk (12KB) / ep[3][32][66]
    const int tid  = threadIdx.x;
    const int lane = tid & 63;
    const int w    = __builtin_amdgcn_readfirstlane(tid >> 6);   // 0..3
    const int vt   = w;
    const int vb4  = blockIdx.y * 4;
    const int bblk = blockIdx.x;
    const int nbt  = B >> 4;

    f32x4 acc[3][4];
    #pragma unroll
    for (int c = 0; c < 3; ++c)
        #pragma unroll
        for (int bt = 0; bt < 4; ++bt) {
            acc[c][bt][0] = 0.f; acc[c][bt][1] = 0.f; acc[c][bt][2] = 0.f; acc[c][bt][3] = 0.f;
        }

    // T14 async staging: prologue load of chunk 0 into regs
    const int row0 = tid, row1 = tid + 256, row2 = tid + 512;
    const int ch0 = row0 >> 6, l20 = row0 & 63;
    const int ch1 = row1 >> 6, l21 = row1 & 63;
    const int ch2 = row2 >> 6, l22 = row2 & 63;
    float4 nxt0 = dirsF[((size_t)(ch0 >> 2) * NVT + vb4 + (ch0 & 3)) * 64 + l20];
    float4 nxt1 = dirsF[((size_t)(ch1 >> 2) * NVT + vb4 + (ch1 & 3)) * 64 + l21];
    float4 nxt2 = dirsF[((size_t)(ch2 >> 2) * NVT + vb4 + (ch2 & 3)) * 64 + l22];

    for (int kt = 0; kt < 7; ++kt) {
        __syncthreads();   // previous MFMA ds_reads done before overwrite
        *(float4*)&smem[row0 * 4] = nxt0;
        *(float4*)&smem[row1 * 4] = nxt1;
        *(float4*)&smem[row2 * 4] = nxt2;
        if (kt < 6) {      // issue next-chunk loads; latency hides under MFMA
            nxt0 = dirsF[((size_t)((kt + 1) * 3 + (ch0 >> 2)) * NVT + vb4 + (ch0 & 3)) * 64 + l20];
            nxt1 = dirsF[((size_t)((kt + 1) * 3 + (ch1 >> 2)) * NVT + vb4 + (ch1 & 3)) * 64 + l21];
            nxt2 = dirsF[((size_t)((kt + 1) * 3 + (ch2 >> 2)) * NVT + vb4 + (ch2 & 3)) * 64 + l22];
        }
        __syncthreads();
        bf16x8 bq[4];
        #pragma unroll
        for (int bt = 0; bt < 4; ++bt)
            bq[bt] = *(const bf16x8*)&coeffF[((size_t)kt * nbt + bblk * 4 + bt) * 64 + lane];
        #pragma unroll
        for (int c = 0; c < 3; ++c) {
            const bf16x8 a = *(const bf16x8*)&smem[((c * 4 + vt) * 64 + lane) * 4];
            #pragma unroll
            for (int bt = 0; bt < 4; ++bt)
                acc[c][bt] = __builtin_amdgcn_mfma_f32_16x16x32_bf16(a, bq[bt], acc[c][bt], 0, 0, 0);
        }
    }

    // add v_template (certified)
    const int vrow0 = (vb4 + vt) * 16 + ((lane >> 4) << 2);
    #pragma unroll
    for (int c = 0; c < 3; ++c) {
        float tv[4];
        #pragma unroll
        for (int r = 0; r < 4; ++r) {
            const int v = vrow0 + r;
            tv[r] = (v < NV) ? v_template[(size_t)v * 3 + c] : 0.f;
        }
        #pragma unroll
        for (int bt = 0; bt < 4; ++bt) {
            acc[c][bt][0] += tv[0]; acc[c][bt][1] += tv[1];
            acc[c][bt][2] += tv[2]; acc[c][bt][3] += tv[3];
        }
    }

    // in-register weight A-frags (certified R7)
    bf16x8 wh, wl;
    {
        const int vA = (vb4 + vt) * 16 + (lane & 15);
        const int kg = lane >> 4;
        if (kg < 3 && vA < NV) {
            const float* wp = weights + (size_t)vA * NJ + kg * 8;
            #pragma unroll
            for (int i = 0; i < 8; ++i) {
                const float val = wp[i];
                const unsigned short hi = f2bf(val);
                wh[i] = (short)hi;
                wl[i] = (short)f2bf(val - bf2f(hi));
            }
        } else {
            #pragma unroll
            for (int i = 0; i < 8; ++i) { wh[i] = 0; wl[i] = 0; }
        }
    }

    __syncthreads();   // all waves done reading dirs LDS

    f32x4 zero; zero[0] = 0.f; zero[1] = 0.f; zero[2] = 0.f; zero[3] = 0.f;

    for (int p = 0; p < 2; ++p) {
        if (p) __syncthreads();   // pass-0 readers done before ep overwrite
        #pragma unroll
        for (int half = 0; half < 2; ++half) {
            const int bt = 2 * p + half;
            #pragma unroll
            for (int C = 0; C < 3; ++C) {
                const size_t baseT  = (((size_t)bblk * 12 + (C * 4 + 3)) * 4 + bt) * 64 + lane;
                const size_t baseTL = (((size_t)bblk * 3 + C) * 4 + bt) * 64 + lane;
                const bf16x8 ATh = *(const bf16x8*)&AF[baseT];
                const bf16x8 ATl = *(const bf16x8*)&AFL[baseTL];
                f32x4 out = __builtin_amdgcn_mfma_f32_16x16x32_bf16(wl, ATh, zero, 0, 0, 0);
                out = __builtin_amdgcn_mfma_f32_16x16x32_bf16(wh, ATl, out, 0, 0, 0);
                out = __builtin_amdgcn_mfma_f32_16x16x32_bf16(wh, ATh, out, 0, 0, 0);
                #pragma unroll
                for (int q = 0; q < 3; ++q) {
                    const size_t baseR = (((size_t)bblk * 12 + (C * 4 + q)) * 4 + bt) * 64 + lane;
                    const bf16x8 ARh = *(const bf16x8*)&AF[baseR];
                    f32x4 rr = __builtin_amdgcn_mfma_f32_16x16x32_bf16(wl, ARh, zero, 0, 0, 0);
                    rr = __builtin_amdgcn_mfma_f32_16x16x32_bf16(wh, ARh, rr, 0, 0, 0);
                    out[0] = fmaf(rr[0], acc[q][bt][0], out[0]);
                    out[1] = fmaf(rr[1], acc[q][bt][1], out[1]);
                    out[2] = fmaf(rr[2], acc[q][bt][2], out[2]);
                    out[3] = fmaf(rr[3], acc[q][bt][3], out[3]);
                }
                // ep write — R6-certified mapping
                const int b32 = half * 16 + (lane & 15);
                const int vl  = vt * 16 + ((lane >> 4) << 2);
                smem[(C * 32 + b32) * 66 + vl + 0] = out[0];
                smem[(C * 32 + b32) * 66 + vl + 1] = out[1];
                smem[(C * 32 + b32) * 66 + vl + 2] = out[2];
                smem[(C * 32 + b32) * 66 + vl + 3] = out[3];
            }
        }
        __syncthreads();

        // full-line contiguous store: 32 rows x 192 floats, as float2 runs.
        // Each wave instruction covers 512 B contiguous -> no partial lines.
        #pragma unroll
        for (int it = 0; it < 12; ++it) {
            const int flat2 = it * 256 + tid;          // 0..3071
            const int brow = flat2 / 96;               // 0..31
            const int o2 = flat2 - brow * 96;          // 0..95
            const int j0 = o2 * 2;
            const int vl0 = j0 / 3, c0 = j0 - vl0 * 3;
            const int j1 = j0 + 1;
            const int vl1 = j1 / 3, c1 = j1 - vl1 * 3;
            const float x = smem[(c0 * 32 + brow) * 66 + vl0];
            const float y = smem[(c1 * 32 + brow) * 66 + vl1];
            const int vg1 = vb4 * 16 + vl1;            // vl1 >= vl0
            const int b = bblk * 64 + p * 32 + brow;
            float* dst = vert_out + (size_t)b * (NV * 3) + (size_t)vb4 * 48 + j0;
            if (vg1 < NV) {
                *(float2*)dst = make_float2(x, y);     // 8-B aligned always
            } else if (vb4 * 16 + vl0 < NV) {
                dst[0] = x;
            }
        }
    }
}

// ---------------------------------------------------------------------------
extern "C" void kernel_launch(void* const* d_in, const int* in_sizes, int n_in,
                              void* d_out, int out_size, void* d_ws, size_t ws_size,
                              hipStream_t stream) {
    const float* pose        = (const float*)d_in[0];
    const float* betas       = (const float*)d_in[1];
    const float* trans       = (const float*)d_in[2];
    const float* v_template  = (const float*)d_in[3];
    const float* shapedirs   = (const float*)d_in[4];
    const float* posedirs    = (const float*)d_in[5];
    const float* J_template  = (const float*)d_in[6];
    const float* J_shapedirs = (const float*)d_in[7];
    const float* weights     = (const float*)d_in[8];
    const int B = in_sizes[0] / 72;   // 1024

    float* out = (float*)d_out;
    float* joints_out = out;                                        // B*72
    float* vert_out   = out + (size_t)B * 72;                       // B*NV*3
    float* glob_out   = out + (size_t)B * 72 + (size_t)B * NV * 3;  // B*216

    char* ws = (char*)d_ws;
    const size_t coeff_bytes = (size_t)7 * (B >> 4) * 64 * 16;       // 458,752
    const size_t af_bytes    = (size_t)(B >> 6) * 12 * 4 * 64 * 16;  // 786,432
    const size_t afl_bytes   = (size_t)(B >> 6) * 3 * 4 * 64 * 16;   // 196,608
    unsigned short* coeffF = (unsigned short*)ws;
    unsigned short* AF     = (unsigned short*)(ws + coeff_bytes);
    unsigned short* AFL    = (unsigned short*)(ws + coeff_bytes + af_bytes);
    unsigned short* dirsF  = (unsigned short*)(ws + coeff_bytes + af_bytes + afl_bytes);

    pack_kernel<<<dim3(NVT), 256, 0, stream>>>(shapedirs, posedirs, dirsF);
    prep_kernel<<<dim3(B), 64, 0, stream>>>(pose, betas, trans, J_template, J_shapedirs,
                                            joints_out, glob_out, AF, AFL, coeffF, B);
    vert_kernel<<<dim3(B / 64, 108), 256, 0, stream>>>((const float4*)dirsF, (const float4*)coeffF,
                                                       (const float4*)AF, (const float4*)AFL,
                                                       v_template, weights, vert_out, B);
}